// Round 6
// baseline (2504.073 us; speedup 1.0000x reference)
//
#include <hip/hip_runtime.h>
#include <math.h>

#define LNUM 16
#define D 256
#define FF 512
#define NH 8
#define NE 12
#define HD 32
#define BB 4
#define SS 512
#define NT 2048      // B*S
#define EPS 1e-5f
#define MAXT 48
#define PADROWS 5632

typedef _Float16 f16;
typedef __attribute__((ext_vector_type(8))) _Float16 f16x8;
typedef __attribute__((ext_vector_type(4))) _Float16 f16x4;
typedef __attribute__((ext_vector_type(4))) float f32x4;
#define MFMA(A, B, C) __builtin_amdgcn_mfma_f32_16x16x32_f16((A), (B), (C), 0, 0, 0)

__device__ inline void splitf(float x, f16& h, f16& l) {
  f16 hh = (f16)x;
  h = hh;
  l = (f16)(x - (float)hh);
}

// ---------------- weight prep: [K][N] fp32 -> hi/lo [N][K] f16 (per-mat z) ----------------
__global__ __launch_bounds__(256) void k_wprep(const float* __restrict__ src,
                                               f16* __restrict__ dh, f16* __restrict__ dl,
                                               int K, int N) {
  const size_t msz = (size_t)K * N * blockIdx.z;
  src += msz; dh += msz; dl += msz;
  const int n0 = blockIdx.x * 32, k0 = blockIdx.y * 32;
  __shared__ f16 th[32][36], tl[32][36];
  const int t = threadIdx.x;
  {
    const int r = t >> 3, c4 = (t & 7) * 4;
    float4 v = *(const float4*)(src + (size_t)(k0 + r) * N + n0 + c4);
    f16 h0, l0, h1, l1, h2, l2, h3, l3;
    splitf(v.x, h0, l0); splitf(v.y, h1, l1);
    splitf(v.z, h2, l2); splitf(v.w, h3, l3);
    th[c4 + 0][r] = h0; tl[c4 + 0][r] = l0;
    th[c4 + 1][r] = h1; tl[c4 + 1][r] = l1;
    th[c4 + 2][r] = h2; tl[c4 + 2][r] = l2;
    th[c4 + 3][r] = h3; tl[c4 + 3][r] = l3;
  }
  __syncthreads();
  const int rn = t >> 3, ck = (t & 7) * 4;
  f16x4 hv, lv;
#pragma unroll
  for (int j = 0; j < 4; j++) { hv[j] = th[rn][ck + j]; lv[j] = tl[rn][ck + j]; }
  *(f16x4*)(dh + (size_t)(n0 + rn) * K + k0 + ck) = hv;
  *(f16x4*)(dl + (size_t)(n0 + rn) * K + k0 + ck) = lv;
}

// ---------------- embedding gather + split ----------------
__global__ __launch_bounds__(256) void k_embed(const int* __restrict__ tok,
                                               const float* __restrict__ emb,
                                               float* __restrict__ x,
                                               f16* __restrict__ xh, f16* __restrict__ xl) {
  int n = blockIdx.x, t = threadIdx.x;
  float val = emb[(size_t)tok[n] * D + t];
  x[(size_t)n * D + t] = val;
  f16 h, l; splitf(val, h, l);
  xh[(size_t)n * D + t] = h;
  xl[(size_t)n * D + t] = l;
}

// ---------------- QKV projection: barrier-free direct-fragment GEMM ----------------
// grid (16 row-tiles, 12 col-tiles[3 mats x 4]), 256 thr = 4 independent waves (32x64 each)
__global__ __launch_bounds__(256) void k_qkv_mfma(
    const f16* __restrict__ xh, const f16* __restrict__ xl,
    const f16* __restrict__ wqh, const f16* __restrict__ wql, const float* __restrict__ bq,
    const f16* __restrict__ wkh, const f16* __restrict__ wkl, const float* __restrict__ bk,
    const f16* __restrict__ wvh, const f16* __restrict__ wvl, const float* __restrict__ bv,
    f16* __restrict__ qhb, f16* __restrict__ qlb,
    f16* __restrict__ khb, f16* __restrict__ klb,
    f16* __restrict__ vhb, f16* __restrict__ vlb) {
  const int mat = blockIdx.y >> 2;
  const f16* Wh; const f16* Wl; const float* bias; f16* outh; f16* outl;
  if (mat == 0)      { Wh = wqh; Wl = wql; bias = bq; outh = qhb; outl = qlb; }
  else if (mat == 1) { Wh = wkh; Wl = wkl; bias = bk; outh = khb; outl = klb; }
  else               { Wh = wvh; Wl = wvl; bias = bv; outh = vhb; outl = vlb; }
  const int row0 = blockIdx.x * 128, col0 = (blockIdx.y & 3) * 64;
  const int tid = threadIdx.x;
  const int lane = tid & 63, w = tid >> 6;
  const int lm = lane & 15, lg = lane >> 4, lk = lg * 8;
  f32x4 acc[2][4] = {};
  const f16* arow0h = xh + (size_t)(row0 + w * 32 + lm) * D + lk;
  const f16* arow0l = xl + (size_t)(row0 + w * 32 + lm) * D + lk;
  const f16* bcolh = Wh + (size_t)(col0 + lm) * D + lk;
  const f16* bcoll = Wl + (size_t)(col0 + lm) * D + lk;
#pragma unroll 2
  for (int k0 = 0; k0 < D; k0 += 32) {
    f16x8 a_h[2], a_l[2];
#pragma unroll
    for (int mt = 0; mt < 2; mt++) {
      a_h[mt] = *(const f16x8*)(arow0h + (size_t)mt * 16 * D + k0);
      a_l[mt] = *(const f16x8*)(arow0l + (size_t)mt * 16 * D + k0);
    }
#pragma unroll
    for (int nt = 0; nt < 4; nt++) {
      f16x8 b_h = *(const f16x8*)(bcolh + (size_t)nt * 16 * D + k0);
      f16x8 b_l = *(const f16x8*)(bcoll + (size_t)nt * 16 * D + k0);
#pragma unroll
      for (int mt = 0; mt < 2; mt++) {
        f32x4 c = acc[mt][nt];
        c = MFMA(a_h[mt], b_h, c);
        c = MFMA(a_h[mt], b_l, c);
        c = MFMA(a_l[mt], b_h, c);
        acc[mt][nt] = c;
      }
    }
  }
#pragma unroll
  for (int mt = 0; mt < 2; mt++)
#pragma unroll
    for (int nt = 0; nt < 4; nt++) {
      int col = col0 + nt * 16 + lm;
      float bv_ = bias[col];
#pragma unroll
      for (int r = 0; r < 4; r++) {
        int row = row0 + w * 32 + mt * 16 + lg * 4 + r;
        float val = acc[mt][nt][r] + bv_;
        f16 h16, l16; splitf(val, h16, l16);
        outh[(size_t)row * D + col] = h16;
        outl[(size_t)row * D + col] = l16;
      }
    }
}

// ---------------- MFMA flash attention (no 1/sqrt(d) scale, per reference) ----------------
// grid (8 row-tiles, 32 b*h), 256 thr (4 waves, 16 q-rows each)
// Q/K fragments direct from global (L2-resident); V staged transposed in LDS with
// register prefetch of the next tile (latency hidden under softmax+PV).
__global__ __launch_bounds__(256) void k_attn_mfma(
    const f16* __restrict__ qh, const f16* __restrict__ ql,
    const f16* __restrict__ kh, const f16* __restrict__ kl,
    const f16* __restrict__ vh, const f16* __restrict__ vl,
    float* __restrict__ o) {
  const int rt = blockIdx.x, bh = blockIdx.y;
  const int b = bh >> 3, h = bh & 7;
  const int row0 = rt * 64;
  __shared__ f16 Vth[32][72], Vtl[32][72];
  __shared__ f16 Ph[4][16][72], Pl[4][16][72];
  const int tid = threadIdx.x;
  const int lane = tid & 63, w = tid >> 6;
  const int lm = lane & 15, lg = lane >> 4, lk = lg * 8;
  const int sr = tid >> 2, sc = (tid & 3) * 8;
  // Q fragments: direct global, loaded once
  const size_t gq = (size_t)(b * SS + row0 + w * 16 + lm) * D + h * HD + lk;
  const f16x8 qfh = *(const f16x8*)(qh + gq);
  const f16x8 qfl = *(const f16x8*)(ql + gq);
  // V prefetch (tile 0)
  f16x8 vrh = *(const f16x8*)(vh + (size_t)(b * SS + sr) * D + h * HD + sc);
  f16x8 vrl = *(const f16x8*)(vl + (size_t)(b * SS + sr) * D + h * HD + sc);
  f32x4 accO[2] = {};
  float mrow[4], lsum[4];
#pragma unroll
  for (int r = 0; r < 4; r++) { mrow[r] = -1e30f; lsum[r] = 0.f; }
  for (int ct = 0; ct <= rt; ct++) {
    // QK^T via direct-global K fragments
    f32x4 s[4];
    const f16* kbase_h = kh + (size_t)(b * SS + ct * 64 + lm) * D + h * HD + lk;
    const f16* kbase_l = kl + (size_t)(b * SS + ct * 64 + lm) * D + h * HD + lk;
#pragma unroll
    for (int nt = 0; nt < 4; nt++) {
      f16x8 kfh = *(const f16x8*)(kbase_h + (size_t)nt * 16 * D);
      f16x8 kfl = *(const f16x8*)(kbase_l + (size_t)nt * 16 * D);
      f32x4 c = {};
      c = MFMA(qfh, kfh, c);
      c = MFMA(qfh, kfl, c);
      c = MFMA(qfl, kfh, c);
      s[nt] = c;
    }
    if (ct == rt) {
#pragma unroll
      for (int nt = 0; nt < 4; nt++)
#pragma unroll
        for (int r = 0; r < 4; r++)
          if (nt * 16 + lm > w * 16 + lg * 4 + r) s[nt][r] = -1e30f;
    }
    __syncthreads();  // previous PV finished reading Vth/Vtl
    {
#pragma unroll
      for (int j = 0; j < 8; j++) { Vth[sc + j][sr] = vrh[j]; Vtl[sc + j][sr] = vrl[j]; }
    }
    if (ct < rt) {  // prefetch next V tile; latency hides under softmax+PV
      vrh = *(const f16x8*)(vh + (size_t)(b * SS + (ct + 1) * 64 + sr) * D + h * HD + sc);
      vrl = *(const f16x8*)(vl + (size_t)(b * SS + (ct + 1) * 64 + sr) * D + h * HD + sc);
    }
    float scal[4];
#pragma unroll
    for (int r = 0; r < 4; r++) {
      float mt2 = fmaxf(fmaxf(s[0][r], s[1][r]), fmaxf(s[2][r], s[3][r]));
      mt2 = fmaxf(mt2, __shfl_xor(mt2, 1));
      mt2 = fmaxf(mt2, __shfl_xor(mt2, 2));
      mt2 = fmaxf(mt2, __shfl_xor(mt2, 4));
      mt2 = fmaxf(mt2, __shfl_xor(mt2, 8));
      float mn = fmaxf(mrow[r], mt2);
      scal[r] = expf(mrow[r] - mn);
      mrow[r] = mn;
    }
    float rs[4] = {0.f, 0.f, 0.f, 0.f};
#pragma unroll
    for (int nt = 0; nt < 4; nt++)
#pragma unroll
      for (int r = 0; r < 4; r++) {
        float pv = expf(s[nt][r] - mrow[r]);
        rs[r] += pv;
        f16 ph16, pl16; splitf(pv, ph16, pl16);
        Ph[w][lg * 4 + r][nt * 16 + lm] = ph16;
        Pl[w][lg * 4 + r][nt * 16 + lm] = pl16;
      }
#pragma unroll
    for (int r = 0; r < 4; r++) {
      rs[r] += __shfl_xor(rs[r], 1);
      rs[r] += __shfl_xor(rs[r], 2);
      rs[r] += __shfl_xor(rs[r], 4);
      rs[r] += __shfl_xor(rs[r], 8);
      lsum[r] = lsum[r] * scal[r] + rs[r];
      accO[0][r] *= scal[r];
      accO[1][r] *= scal[r];
    }
    __syncthreads();  // Vth/Vtl ready
#pragma unroll
    for (int ct2 = 0; ct2 < 2; ct2++)
#pragma unroll
      for (int ks = 0; ks < 2; ks++) {
        f16x8 pa_h = *(const f16x8*)&Ph[w][lm][ks * 32 + lk];
        f16x8 pa_l = *(const f16x8*)&Pl[w][lm][ks * 32 + lk];
        f16x8 vb_h = *(const f16x8*)&Vth[ct2 * 16 + lm][ks * 32 + lk];
        f16x8 vb_l = *(const f16x8*)&Vtl[ct2 * 16 + lm][ks * 32 + lk];
        accO[ct2] = MFMA(pa_h, vb_h, accO[ct2]);
        accO[ct2] = MFMA(pa_h, vb_l, accO[ct2]);
        accO[ct2] = MFMA(pa_l, vb_h, accO[ct2]);
      }
  }
#pragma unroll
  for (int ct2 = 0; ct2 < 2; ct2++)
#pragma unroll
    for (int r = 0; r < 4; r++) {
      int grow = row0 + w * 16 + lg * 4 + r;
      o[(size_t)(b * SS + grow) * D + h * HD + ct2 * 16 + lm] = accO[ct2][r] / lsum[r];
    }
}

// ---------------- wave-per-token: residual + LN1 + gate + top-2 ----------------
// grid 512, 256 thr (4 waves = 4 tokens)
__global__ __launch_bounds__(256) void k_ln1gate(
    const float* __restrict__ o, const float* __restrict__ x,
    const float* __restrict__ s1, const float* __restrict__ b1,
    const float* __restrict__ gW, const float* __restrict__ gb,
    float* __restrict__ norm, f16* __restrict__ nhb, f16* __restrict__ nlb,
    int* __restrict__ eidx) {
  const int w = threadIdx.x >> 6, lane = threadIdx.x & 63;
  const int n = blockIdx.x * 4 + w;
  float val[4], s1v = 0.f, s2v = 0.f;
#pragma unroll
  for (int j = 0; j < 4; j++) {
    int d = lane + 64 * j;
    float v = o[(size_t)n * D + d] + x[(size_t)n * D + d];
    val[j] = v; s1v += v; s2v += v * v;
  }
#pragma unroll
  for (int m = 1; m < 64; m <<= 1) {
    s1v += __shfl_xor(s1v, m);
    s2v += __shfl_xor(s2v, m);
  }
  float mean = s1v * (1.f / D);
  float var = s2v * (1.f / D) - mean * mean;
  float rstd = rsqrtf(var + EPS);
  float ge[NE];
#pragma unroll
  for (int e = 0; e < NE; e++) ge[e] = 0.f;
#pragma unroll
  for (int j = 0; j < 4; j++) {
    int d = lane + 64 * j;
    float nv = (val[j] - mean) * rstd * s1[d] + b1[d];
    norm[(size_t)n * D + d] = nv;
    f16 h16, l16; splitf(nv, h16, l16);
    nhb[(size_t)n * D + d] = h16;
    nlb[(size_t)n * D + d] = l16;
    const float* gr = gW + (size_t)d * NE;
#pragma unroll
    for (int e = 0; e < NE; e++) ge[e] += nv * gr[e];
  }
#pragma unroll
  for (int m = 1; m < 64; m <<= 1)
#pragma unroll
    for (int e = 0; e < NE; e++) ge[e] += __shfl_xor(ge[e], m);
  if (lane == 0) {
#pragma unroll
    for (int e = 0; e < NE; e++) ge[e] += gb[e];
    int i1 = 0; float v1 = ge[0];
#pragma unroll
    for (int e = 1; e < NE; e++) if (ge[e] > v1) { v1 = ge[e]; i1 = e; }
    int i2 = -1; float v2 = -3.4e38f;
#pragma unroll
    for (int e = 0; e < NE; e++) if (e != i1 && ge[e] > v2) { v2 = ge[e]; i2 = e; }
    eidx[n * 2 + 0] = i1;
    eidx[n * 2 + 1] = i2;
  }
}

// ---------------- routing: counts -> padded 128-row tiles -> scatter ----------------
__global__ __launch_bounds__(256) void k_route(const int* __restrict__ eidx,
                                               int* __restrict__ rlist, int* __restrict__ tokpos,
                                               int* __restrict__ te, int* __restrict__ tbase,
                                               int* __restrict__ tnv) {
  __shared__ int cnt[NE], cur[NE], poff[NE];
  const int t = threadIdx.x;
  if (t < NE) { cnt[t] = 0; cur[t] = 0; }
  __syncthreads();
  for (int n = t; n < NT; n += 256) {
    atomicAdd(&cnt[eidx[n * 2 + 0]], 1);
    atomicAdd(&cnt[eidx[n * 2 + 1]], 1);
  }
  __syncthreads();
  if (t == 0) {
    int off = 0, ti = 0;
    for (int e = 0; e < NE; e++) {
      poff[e] = off;
      int ntl = (cnt[e] + 127) >> 7;
      for (int tt = 0; tt < ntl; tt++) {
        te[ti] = e; tbase[ti] = off + tt * 128;
        int rem = cnt[e] - tt * 128; tnv[ti] = rem < 128 ? rem : 128;
        ti++;
      }
      off += ntl * 128;
    }
    for (; ti < MAXT; ti++) te[ti] = -1;
  }
  __syncthreads();
  for (int n = t; n < NT; n += 256) {
#pragma unroll
    for (int s2 = 0; s2 < 2; s2++) {
      int e = eidx[n * 2 + s2];
      int pos = atomicAdd(&cur[e], 1);
      int row = poff[e] + pos;
      rlist[row] = n;
      tokpos[n * 2 + s2] = row;
    }
  }
}

// ---------------- MoE up-projection: barrier-free direct-fragment GEMM ----------------
// grid (MAXT, 8), 256 thr = 4 independent waves (32x64)
__global__ __launch_bounds__(256) void k_ff1_mfma(
    const f16* __restrict__ nhb, const f16* __restrict__ nlb,
    const int* __restrict__ rlist,
    const int* __restrict__ te, const int* __restrict__ tbase, const int* __restrict__ tnv,
    const f16* __restrict__ w1th, const f16* __restrict__ w1tl, const float* __restrict__ b1f,
    const f16* __restrict__ wgth, const f16* __restrict__ wgtl, const float* __restrict__ bgf,
    f16* __restrict__ hhb, f16* __restrict__ hlb) {
  const int mt0 = blockIdx.x;
  const int e = te[mt0];
  if (e < 0) return;
  const int base = tbase[mt0], nv = tnv[mt0];
  const int col0 = blockIdx.y * 64;
  const f16* W1h = w1th + (size_t)e * D * FF + (size_t)(col0) * D;
  const f16* W1l = w1tl + (size_t)e * D * FF + (size_t)(col0) * D;
  const f16* Wgh = wgth + (size_t)e * D * FF + (size_t)(col0) * D;
  const f16* Wgl = wgtl + (size_t)e * D * FF + (size_t)(col0) * D;
  const int tid = threadIdx.x;
  const int lane = tid & 63, w = tid >> 6;
  const int lm = lane & 15, lg = lane >> 4, lk = lg * 8;
  // gathered A rows (one per mt sub-tile)
  int ra[2];
#pragma unroll
  for (int mt = 0; mt < 2; mt++) {
    int slot = w * 32 + mt * 16 + lm;
    ra[mt] = (slot < nv) ? rlist[base + slot] : 0;
  }
  f32x4 acc1[2][4] = {}, acc2[2][4] = {};
#pragma unroll 2
  for (int k0 = 0; k0 < D; k0 += 32) {
    f16x8 a_h[2], a_l[2];
#pragma unroll
    for (int mt = 0; mt < 2; mt++) {
      a_h[mt] = *(const f16x8*)(nhb + (size_t)ra[mt] * D + k0 + lk);
      a_l[mt] = *(const f16x8*)(nlb + (size_t)ra[mt] * D + k0 + lk);
    }
#pragma unroll
    for (int nt = 0; nt < 4; nt++) {
      size_t gb = (size_t)(nt * 16 + lm) * D + k0 + lk;
      f16x8 b_h = *(const f16x8*)(W1h + gb);
      f16x8 b_l = *(const f16x8*)(W1l + gb);
      f16x8 c_h = *(const f16x8*)(Wgh + gb);
      f16x8 c_l = *(const f16x8*)(Wgl + gb);
#pragma unroll
      for (int mt = 0; mt < 2; mt++) {
        f32x4 c1 = acc1[mt][nt];
        c1 = MFMA(a_h[mt], b_h, c1);
        c1 = MFMA(a_h[mt], b_l, c1);
        c1 = MFMA(a_l[mt], b_h, c1);
        acc1[mt][nt] = c1;
        f32x4 c2 = acc2[mt][nt];
        c2 = MFMA(a_h[mt], c_h, c2);
        c2 = MFMA(a_h[mt], c_l, c2);
        c2 = MFMA(a_l[mt], c_h, c2);
        acc2[mt][nt] = c2;
      }
    }
  }
#pragma unroll
  for (int mt = 0; mt < 2; mt++)
#pragma unroll
    for (int nt = 0; nt < 4; nt++) {
      int col = col0 + nt * 16 + lm;
      float bb1 = b1f[e * FF + col], bb2 = bgf[e * FF + col];
#pragma unroll
      for (int r = 0; r < 4; r++) {
        int rit = w * 32 + mt * 16 + lg * 4 + r;
        if (rit < nv) {
          float z1 = acc1[mt][nt][r] + bb1;
          float zg = acc2[mt][nt][r] + bb2;
          float sl = z1 / (1.f + expf(-z1));
          float hv = sl * zg;
          f16 h16, l16; splitf(hv, h16, l16);
          hhb[(size_t)(base + rit) * FF + col] = h16;
          hlb[(size_t)(base + rit) * FF + col] = l16;
        }
      }
    }
}

// ---------------- MoE down-projection: barrier-free direct-fragment GEMM ----------------
// grid (MAXT, 4), 256 thr = 4 independent waves (32x64)
__global__ __launch_bounds__(256) void k_ff2_mfma(
    const f16* __restrict__ hhb, const f16* __restrict__ hlb,
    const int* __restrict__ te, const int* __restrict__ tbase, const int* __restrict__ tnv,
    const f16* __restrict__ w2th, const f16* __restrict__ w2tl, const float* __restrict__ b2f,
    float* __restrict__ ybuf) {
  const int mt0 = blockIdx.x;
  const int e = te[mt0];
  if (e < 0) return;
  const int base = tbase[mt0], nv = tnv[mt0];
  const int col0 = blockIdx.y * 64;
  const f16* W2h = w2th + (size_t)e * FF * D + (size_t)col0 * FF;
  const f16* W2l = w2tl + (size_t)e * FF * D + (size_t)col0 * FF;
  const int tid = threadIdx.x;
  const int lane = tid & 63, w = tid >> 6;
  const int lm = lane & 15, lg = lane >> 4, lk = lg * 8;
  const f16* arowh = hhb + (size_t)(base + w * 32 + lm) * FF + lk;
  const f16* arowl = hlb + (size_t)(base + w * 32 + lm) * FF + lk;
  f32x4 acc[2][4] = {};
#pragma unroll 2
  for (int k0 = 0; k0 < FF; k0 += 32) {
    f16x8 a_h[2], a_l[2];
#pragma unroll
    for (int mt = 0; mt < 2; mt++) {
      a_h[mt] = *(const f16x8*)(arowh + (size_t)mt * 16 * FF + k0);
      a_l[mt] = *(const f16x8*)(arowl + (size_t)mt * 16 * FF + k0);
    }
#pragma unroll
    for (int nt = 0; nt < 4; nt++) {
      size_t gb = (size_t)(nt * 16 + lm) * FF + k0 + lk;
      f16x8 b_h = *(const f16x8*)(W2h + gb);
      f16x8 b_l = *(const f16x8*)(W2l + gb);
#pragma unroll
      for (int mt = 0; mt < 2; mt++) {
        f32x4 c = acc[mt][nt];
        c = MFMA(a_h[mt], b_h, c);
        c = MFMA(a_h[mt], b_l, c);
        c = MFMA(a_l[mt], b_h, c);
        acc[mt][nt] = c;
      }
    }
  }
#pragma unroll
  for (int mt = 0; mt < 2; mt++)
#pragma unroll
    for (int nt = 0; nt < 4; nt++) {
      int col = col0 + nt * 16 + lm;
      float bb = b2f[e * D + col];
#pragma unroll
      for (int r = 0; r < 4; r++) {
        int rit = w * 32 + mt * 16 + lg * 4 + r;
        if (rit < nv) ybuf[(size_t)(base + rit) * D + col] = acc[mt][nt][r] + bb;
      }
    }
}

// ---------------- wave-per-token: moe-sum + residual + LN2 + split ----------------
// grid 512, 256 thr
__global__ __launch_bounds__(256) void k_ln2(
    const float* __restrict__ ybuf, const int* __restrict__ tokpos,
    const float* __restrict__ norm, const float* __restrict__ s2, const float* __restrict__ b2,
    float* __restrict__ dst, f16* __restrict__ xh, f16* __restrict__ xl) {
  const int w = threadIdx.x >> 6, lane = threadIdx.x & 63;
  const int n = blockIdx.x * 4 + w;
  const int p0 = tokpos[n * 2 + 0], p1 = tokpos[n * 2 + 1];
  float val[4], s1v = 0.f, s2v = 0.f;
#pragma unroll
  for (int j = 0; j < 4; j++) {
    int d = lane + 64 * j;
    float v = ybuf[(size_t)p0 * D + d] + ybuf[(size_t)p1 * D + d] + norm[(size_t)n * D + d];
    val[j] = v; s1v += v; s2v += v * v;
  }
#pragma unroll
  for (int m = 1; m < 64; m <<= 1) {
    s1v += __shfl_xor(s1v, m);
    s2v += __shfl_xor(s2v, m);
  }
  float mean = s1v * (1.f / D);
  float var = s2v * (1.f / D) - mean * mean;
  float rstd = rsqrtf(var + EPS);
#pragma unroll
  for (int j = 0; j < 4; j++) {
    int d = lane + 64 * j;
    float ov = (val[j] - mean) * rstd * s2[d] + b2[d];
    dst[(size_t)n * D + d] = ov;
    f16 h16, l16; splitf(ov, h16, l16);
    xh[(size_t)n * D + d] = h16;
    xl[(size_t)n * D + d] = l16;
  }
}

extern "C" void kernel_launch(void* const* d_in, const int* in_sizes, int n_in,
                              void* d_out, int out_size, void* d_ws, size_t ws_size,
                              hipStream_t stream) {
  (void)in_sizes; (void)n_in; (void)out_size; (void)ws_size;
  const int*   tok = (const int*)d_in[0];
  const float* emb = (const float*)d_in[1];
  const float* Wq  = (const float*)d_in[2];
  const float* bq  = (const float*)d_in[3];
  const float* Wk  = (const float*)d_in[4];
  const float* bk  = (const float*)d_in[5];
  const float* Wv  = (const float*)d_in[6];
  const float* bv  = (const float*)d_in[7];
  const float* l1s = (const float*)d_in[8];
  const float* l1b = (const float*)d_in[9];
  const float* l2s = (const float*)d_in[10];
  const float* l2b = (const float*)d_in[11];
  const float* gW  = (const float*)d_in[12];
  const float* gb  = (const float*)d_in[13];
  const float* f1W = (const float*)d_in[14];
  const float* f1b = (const float*)d_in[15];
  const float* fgW = (const float*)d_in[16];
  const float* fgb = (const float*)d_in[17];
  const float* f2W = (const float*)d_in[18];
  const float* f2b = (const float*)d_in[19];
  float* out = (float*)d_out;

  char* p = (char*)d_ws;
  auto alloc = [&](size_t bytes) { char* r = p; p += (bytes + 255) & ~(size_t)255; return r; };
  // activations
  float* xb = (float*)alloc((size_t)NT * D * 4);
  f16* xh = (f16*)alloc((size_t)NT * D * 2);
  f16* xl = (f16*)alloc((size_t)NT * D * 2);
  f16* qhb = (f16*)alloc((size_t)NT * D * 2);
  f16* qlb = (f16*)alloc((size_t)NT * D * 2);
  f16* khb = (f16*)alloc((size_t)NT * D * 2);
  f16* klb = (f16*)alloc((size_t)NT * D * 2);
  f16* vhb = (f16*)alloc((size_t)NT * D * 2);
  f16* vlb = (f16*)alloc((size_t)NT * D * 2);
  float* ob = (float*)alloc((size_t)NT * D * 4);
  float* nb = (float*)alloc((size_t)NT * D * 4);
  f16* nhb = (f16*)alloc((size_t)NT * D * 2);
  f16* nlb = (f16*)alloc((size_t)NT * D * 2);
  f16* hhb = (f16*)alloc((size_t)PADROWS * FF * 2);
  f16* hlb = (f16*)alloc((size_t)PADROWS * FF * 2);
  float* yb = (float*)alloc((size_t)PADROWS * D * 4);
  int* eidx   = (int*)alloc((size_t)NT * 2 * 4);
  int* rlist  = (int*)alloc((size_t)PADROWS * 4);
  int* tokpos = (int*)alloc((size_t)NT * 2 * 4);
  int* te     = (int*)alloc(MAXT * 4);
  int* tbase  = (int*)alloc(MAXT * 4);
  int* tnv    = (int*)alloc(MAXT * 4);
  // pre-split/transposed weights
  size_t qkvsz = (size_t)LNUM * D * D;        // per hi/lo, elements
  size_t ffsz  = (size_t)LNUM * NE * D * FF;  // per hi/lo, elements
  f16* wqh = (f16*)alloc(qkvsz * 2); f16* wql = (f16*)alloc(qkvsz * 2);
  f16* wkh = (f16*)alloc(qkvsz * 2); f16* wkl = (f16*)alloc(qkvsz * 2);
  f16* wvh = (f16*)alloc(qkvsz * 2); f16* wvl = (f16*)alloc(qkvsz * 2);
  f16* w1th = (f16*)alloc(ffsz * 2); f16* w1tl = (f16*)alloc(ffsz * 2);
  f16* wgth = (f16*)alloc(ffsz * 2); f16* wgtl = (f16*)alloc(ffsz * 2);
  f16* w2th = (f16*)alloc(ffsz * 2); f16* w2tl = (f16*)alloc(ffsz * 2);

  // ---- weight prep (per launch; deterministic) ----
  k_wprep<<<dim3(D / 32, D / 32, LNUM), 256, 0, stream>>>(Wq, wqh, wql, D, D);
  k_wprep<<<dim3(D / 32, D / 32, LNUM), 256, 0, stream>>>(Wk, wkh, wkl, D, D);
  k_wprep<<<dim3(D / 32, D / 32, LNUM), 256, 0, stream>>>(Wv, wvh, wvl, D, D);
  k_wprep<<<dim3(FF / 32, D / 32, LNUM * NE), 256, 0, stream>>>(f1W, w1th, w1tl, D, FF);
  k_wprep<<<dim3(FF / 32, D / 32, LNUM * NE), 256, 0, stream>>>(fgW, wgth, wgtl, D, FF);
  k_wprep<<<dim3(D / 32, FF / 32, LNUM * NE), 256, 0, stream>>>(f2W, w2th, w2tl, FF, D);

  k_embed<<<NT, 256, 0, stream>>>(tok, emb, xb, xh, xl);

  for (int l = 0; l < LNUM; l++) {
    k_qkv_mfma<<<dim3(16, 12), 256, 0, stream>>>(
        xh, xl,
        wqh + (size_t)l * D * D, wql + (size_t)l * D * D, bq + (size_t)l * D,
        wkh + (size_t)l * D * D, wkl + (size_t)l * D * D, bk + (size_t)l * D,
        wvh + (size_t)l * D * D, wvl + (size_t)l * D * D, bv + (size_t)l * D,
        qhb, qlb, khb, klb, vhb, vlb);
    k_attn_mfma<<<dim3(8, 32), 256, 0, stream>>>(qhb, qlb, khb, klb, vhb, vlb, ob);
    k_ln1gate<<<NT / 4, 256, 0, stream>>>(ob, xb, l1s + (size_t)l * D, l1b + (size_t)l * D,
                                          gW + (size_t)l * D * NE, gb + (size_t)l * NE,
                                          nb, nhb, nlb, eidx);
    k_route<<<1, 256, 0, stream>>>(eidx, rlist, tokpos, te, tbase, tnv);
    k_ff1_mfma<<<dim3(MAXT, 8), 256, 0, stream>>>(
        nhb, nlb, rlist, te, tbase, tnv,
        w1th + (size_t)l * NE * D * FF, w1tl + (size_t)l * NE * D * FF, f1b + (size_t)l * NE * FF,
        wgth + (size_t)l * NE * D * FF, wgtl + (size_t)l * NE * D * FF, fgb + (size_t)l * NE * FF,
        hhb, hlb);
    k_ff2_mfma<<<dim3(MAXT, 4), 256, 0, stream>>>(
        hhb, hlb, te, tbase, tnv,
        w2th + (size_t)l * NE * FF * D, w2tl + (size_t)l * NE * FF * D, f2b + (size_t)l * NE * D,
        yb);
    k_ln2<<<NT / 4, 256, 0, stream>>>(yb, tokpos, nb, l2s + (size_t)l * D, l2b + (size_t)l * D,
                                      (l == LNUM - 1) ? out : xb, xh, xl);
  }
}

// Round 7
// 2253.614 us; speedup vs baseline: 1.1111x; 1.1111x over previous
//
#include <hip/hip_runtime.h>
#include <math.h>

#define LNUM 16
#define D 256
#define FF 512
#define NH 8
#define NE 12
#define HD 32
#define BB 4
#define SS 512
#define NT 2048      // B*S
#define EPS 1e-5f
#define CAP 512              // max routed rows per expert (input-dependent; ~341 typical)
#define ROWSP (NE * CAP)     // 6144 padded row space

typedef _Float16 f16;
typedef __attribute__((ext_vector_type(8))) _Float16 f16x8;
typedef __attribute__((ext_vector_type(4))) _Float16 f16x4;
typedef __attribute__((ext_vector_type(4))) float f32x4;
#define MFMA(A, B, C) __builtin_amdgcn_mfma_f32_16x16x32_f16((A), (B), (C), 0, 0, 0)

__device__ inline void splitf(float x, f16& h, f16& l) {
  f16 hh = (f16)x;
  h = hh;
  l = (f16)(x - (float)hh);
}

// ---------------- weight prep: [K][N] fp32 -> hi/lo [N][K] f16 (per-mat z) ----------------
__global__ __launch_bounds__(256) void k_wprep(const float* __restrict__ src,
                                               f16* __restrict__ dh, f16* __restrict__ dl,
                                               int K, int N) {
  const size_t msz = (size_t)K * N * blockIdx.z;
  src += msz; dh += msz; dl += msz;
  const int n0 = blockIdx.x * 32, k0 = blockIdx.y * 32;
  __shared__ f16 th[32][36], tl[32][36];
  const int t = threadIdx.x;
  {
    const int r = t >> 3, c4 = (t & 7) * 4;
    float4 v = *(const float4*)(src + (size_t)(k0 + r) * N + n0 + c4);
    f16 h0, l0, h1, l1, h2, l2, h3, l3;
    splitf(v.x, h0, l0); splitf(v.y, h1, l1);
    splitf(v.z, h2, l2); splitf(v.w, h3, l3);
    th[c4 + 0][r] = h0; tl[c4 + 0][r] = l0;
    th[c4 + 1][r] = h1; tl[c4 + 1][r] = l1;
    th[c4 + 2][r] = h2; tl[c4 + 2][r] = l2;
    th[c4 + 3][r] = h3; tl[c4 + 3][r] = l3;
  }
  __syncthreads();
  const int rn = t >> 3, ck = (t & 7) * 4;
  f16x4 hv, lv;
#pragma unroll
  for (int j = 0; j < 4; j++) { hv[j] = th[rn][ck + j]; lv[j] = tl[rn][ck + j]; }
  *(f16x4*)(dh + (size_t)(n0 + rn) * K + k0 + ck) = hv;
  *(f16x4*)(dl + (size_t)(n0 + rn) * K + k0 + ck) = lv;
}

// ---------------- embedding gather + split (+ per-layer routing counter zero) ----------------
__global__ __launch_bounds__(256) void k_embed(const int* __restrict__ tok,
                                               const float* __restrict__ emb,
                                               float* __restrict__ x,
                                               f16* __restrict__ xh, f16* __restrict__ xl,
                                               int* __restrict__ cntbuf) {
  int n = blockIdx.x, t = threadIdx.x;
  if (n == 0 && t < LNUM * NE) cntbuf[t] = 0;
  float val = emb[(size_t)tok[n] * D + t];
  x[(size_t)n * D + t] = val;
  f16 h, l; splitf(val, h, l);
  xh[(size_t)n * D + t] = h;
  xl[(size_t)n * D + t] = l;
}

// ---------------- QKV projection: 128x64 tiles, K-step 64 ----------------
// grid (16 row-tiles, 4 col-chunks, 3 mats), 256 thr
__global__ __launch_bounds__(256) void k_qkv_mfma(
    const f16* __restrict__ xh, const f16* __restrict__ xl,
    const f16* __restrict__ wqh, const f16* __restrict__ wql, const float* __restrict__ bq,
    const f16* __restrict__ wkh, const f16* __restrict__ wkl, const float* __restrict__ bk,
    const f16* __restrict__ wvh, const f16* __restrict__ wvl, const float* __restrict__ bv,
    f16* __restrict__ qhb, f16* __restrict__ qlb,
    f16* __restrict__ khb, f16* __restrict__ klb,
    f16* __restrict__ vhb, f16* __restrict__ vlb) {
  const int mat = blockIdx.z;
  const f16* Wh; const f16* Wl; const float* bias; f16* outh; f16* outl;
  if (mat == 0)      { Wh = wqh; Wl = wql; bias = bq; outh = qhb; outl = qlb; }
  else if (mat == 1) { Wh = wkh; Wl = wkl; bias = bk; outh = khb; outl = klb; }
  else               { Wh = wvh; Wl = wvl; bias = bv; outh = vhb; outl = vlb; }
  const int row0 = blockIdx.x * 128, col0 = blockIdx.y * 64;
  __shared__ f16 Ah[128][72], Al[128][72], Bh[64][72], Bl[64][72];
  const int tid = threadIdx.x;
  const int asr = tid >> 1, asc = (tid & 1) * 32;
  const int bn2 = tid >> 2, bkc = (tid & 3) * 16;
  const int lane = tid & 63, w = tid >> 6;
  const int lm = lane & 15, lg = lane >> 4, lk = lg * 8;
  f32x4 acc[2][4] = {};
  for (int k0 = 0; k0 < D; k0 += 64) {
    {
      size_t ga = (size_t)(row0 + asr) * D + k0 + asc;
#pragma unroll
      for (int j = 0; j < 4; j++) {
        *(f16x8*)&Ah[asr][asc + j * 8] = *(const f16x8*)(xh + ga + j * 8);
        *(f16x8*)&Al[asr][asc + j * 8] = *(const f16x8*)(xl + ga + j * 8);
      }
      size_t gb = (size_t)(col0 + bn2) * D + k0 + bkc;
#pragma unroll
      for (int j = 0; j < 2; j++) {
        *(f16x8*)&Bh[bn2][bkc + j * 8] = *(const f16x8*)(Wh + gb + j * 8);
        *(f16x8*)&Bl[bn2][bkc + j * 8] = *(const f16x8*)(Wl + gb + j * 8);
      }
    }
    __syncthreads();
#pragma unroll
    for (int ks = 0; ks < 2; ks++) {
      f16x8 a_h[2], a_l[2];
#pragma unroll
      for (int mt = 0; mt < 2; mt++) {
        a_h[mt] = *(const f16x8*)&Ah[w * 32 + mt * 16 + lm][ks * 32 + lk];
        a_l[mt] = *(const f16x8*)&Al[w * 32 + mt * 16 + lm][ks * 32 + lk];
      }
#pragma unroll
      for (int nt = 0; nt < 4; nt++) {
        f16x8 b_h = *(const f16x8*)&Bh[nt * 16 + lm][ks * 32 + lk];
        f16x8 b_l = *(const f16x8*)&Bl[nt * 16 + lm][ks * 32 + lk];
#pragma unroll
        for (int mt = 0; mt < 2; mt++) {
          f32x4 c = acc[mt][nt];
          c = MFMA(a_h[mt], b_h, c);
          c = MFMA(a_h[mt], b_l, c);
          c = MFMA(a_l[mt], b_h, c);
          acc[mt][nt] = c;
        }
      }
    }
    __syncthreads();
  }
#pragma unroll
  for (int mt = 0; mt < 2; mt++)
#pragma unroll
    for (int nt = 0; nt < 4; nt++) {
      int col = col0 + nt * 16 + lm;
      float bv_ = bias[col];
#pragma unroll
      for (int r = 0; r < 4; r++) {
        int row = row0 + w * 32 + mt * 16 + lg * 4 + r;
        float val = acc[mt][nt][r] + bv_;
        f16 h16, l16; splitf(val, h16, l16);
        outh[(size_t)row * D + col] = h16;
        outl[(size_t)row * D + col] = l16;
      }
    }
}

// ---------------- MFMA flash attention (no 1/sqrt(d) scale, per reference) ----------------
// grid (8 row-tiles, 32 b*h), 256 thr (4 waves, 16 q-rows each)
__global__ __launch_bounds__(256) void k_attn_mfma(
    const f16* __restrict__ qh, const f16* __restrict__ ql,
    const f16* __restrict__ kh, const f16* __restrict__ kl,
    const f16* __restrict__ vh, const f16* __restrict__ vl,
    float* __restrict__ o) {
  const int rt = blockIdx.x, bh = blockIdx.y;
  const int b = bh >> 3, h = bh & 7;
  const int row0 = rt * 64;
  __shared__ f16 Qh[64][40], Ql[64][40], Kh[64][40], Kl[64][40];
  __shared__ f16 Vth[32][72], Vtl[32][72];
  __shared__ f16 Ph[4][16][72], Pl[4][16][72];
  const int tid = threadIdx.x;
  const int lane = tid & 63, w = tid >> 6;
  const int lm = lane & 15, lg = lane >> 4, lk = lg * 8;
  const int sr = tid >> 2, sc = (tid & 3) * 8;
  {
    size_t gq = (size_t)(b * SS + row0 + sr) * D + h * HD + sc;
    *(f16x8*)&Qh[sr][sc] = *(const f16x8*)(qh + gq);
    *(f16x8*)&Ql[sr][sc] = *(const f16x8*)(ql + gq);
  }
  f32x4 accO[2] = {};
  float mrow[4], lsum[4];
#pragma unroll
  for (int r = 0; r < 4; r++) { mrow[r] = -1e30f; lsum[r] = 0.f; }
  for (int ct = 0; ct <= rt; ct++) {
    __syncthreads();
    {
      size_t gk = (size_t)(b * SS + ct * 64 + sr) * D + h * HD + sc;
      *(f16x8*)&Kh[sr][sc] = *(const f16x8*)(kh + gk);
      *(f16x8*)&Kl[sr][sc] = *(const f16x8*)(kl + gk);
      f16x8 hv = *(const f16x8*)(vh + gk);
      f16x8 lv = *(const f16x8*)(vl + gk);
#pragma unroll
      for (int j = 0; j < 8; j++) { Vth[sc + j][sr] = hv[j]; Vtl[sc + j][sr] = lv[j]; }
    }
    __syncthreads();
    f16x8 qfh = *(const f16x8*)&Qh[w * 16 + lm][lk];
    f16x8 qfl = *(const f16x8*)&Ql[w * 16 + lm][lk];
    f32x4 s[4];
    __builtin_amdgcn_s_setprio(1);
#pragma unroll
    for (int nt = 0; nt < 4; nt++) {
      f16x8 kfh = *(const f16x8*)&Kh[nt * 16 + lm][lk];
      f16x8 kfl = *(const f16x8*)&Kl[nt * 16 + lm][lk];
      f32x4 c = {};
      c = MFMA(qfh, kfh, c);
      c = MFMA(qfh, kfl, c);
      c = MFMA(qfl, kfh, c);
      s[nt] = c;
    }
    __builtin_amdgcn_s_setprio(0);
    if (ct == rt) {
#pragma unroll
      for (int nt = 0; nt < 4; nt++)
#pragma unroll
        for (int r = 0; r < 4; r++)
          if (nt * 16 + lm > w * 16 + lg * 4 + r) s[nt][r] = -1e30f;
    }
    float scal[4];
#pragma unroll
    for (int r = 0; r < 4; r++) {
      float mt2 = fmaxf(fmaxf(s[0][r], s[1][r]), fmaxf(s[2][r], s[3][r]));
      mt2 = fmaxf(mt2, __shfl_xor(mt2, 1));
      mt2 = fmaxf(mt2, __shfl_xor(mt2, 2));
      mt2 = fmaxf(mt2, __shfl_xor(mt2, 4));
      mt2 = fmaxf(mt2, __shfl_xor(mt2, 8));
      float mn = fmaxf(mrow[r], mt2);
      scal[r] = expf(mrow[r] - mn);
      mrow[r] = mn;
    }
    float rs[4] = {0.f, 0.f, 0.f, 0.f};
#pragma unroll
    for (int nt = 0; nt < 4; nt++)
#pragma unroll
      for (int r = 0; r < 4; r++) {
        float pv = expf(s[nt][r] - mrow[r]);
        rs[r] += pv;
        f16 ph16, pl16; splitf(pv, ph16, pl16);
        Ph[w][lg * 4 + r][nt * 16 + lm] = ph16;
        Pl[w][lg * 4 + r][nt * 16 + lm] = pl16;
      }
#pragma unroll
    for (int r = 0; r < 4; r++) {
      rs[r] += __shfl_xor(rs[r], 1);
      rs[r] += __shfl_xor(rs[r], 2);
      rs[r] += __shfl_xor(rs[r], 4);
      rs[r] += __shfl_xor(rs[r], 8);
      lsum[r] = lsum[r] * scal[r] + rs[r];
      accO[0][r] *= scal[r];
      accO[1][r] *= scal[r];
    }
    __builtin_amdgcn_s_setprio(1);
#pragma unroll
    for (int ct2 = 0; ct2 < 2; ct2++)
#pragma unroll
      for (int ks = 0; ks < 2; ks++) {
        f16x8 pa_h = *(const f16x8*)&Ph[w][lm][ks * 32 + lk];
        f16x8 pa_l = *(const f16x8*)&Pl[w][lm][ks * 32 + lk];
        f16x8 vb_h = *(const f16x8*)&Vth[ct2 * 16 + lm][ks * 32 + lk];
        f16x8 vb_l = *(const f16x8*)&Vtl[ct2 * 16 + lm][ks * 32 + lk];
        accO[ct2] = MFMA(pa_h, vb_h, accO[ct2]);
        accO[ct2] = MFMA(pa_h, vb_l, accO[ct2]);
        accO[ct2] = MFMA(pa_l, vb_h, accO[ct2]);
      }
    __builtin_amdgcn_s_setprio(0);
  }
#pragma unroll
  for (int ct2 = 0; ct2 < 2; ct2++)
#pragma unroll
    for (int r = 0; r < 4; r++) {
      int grow = row0 + w * 16 + lg * 4 + r;
      o[(size_t)(b * SS + grow) * D + h * HD + ct2 * 16 + lm] = accO[ct2][r] / lsum[r];
    }
}

// ---------------- wave-per-token: residual + LN1 + gate + top-2 + atomic routing ----------------
// grid 512, 256 thr (4 waves = 4 tokens)
__global__ __launch_bounds__(256) void k_ln1gate(
    const float* __restrict__ o, const float* __restrict__ x,
    const float* __restrict__ s1, const float* __restrict__ b1,
    const float* __restrict__ gW, const float* __restrict__ gb,
    float* __restrict__ norm, f16* __restrict__ nhb, f16* __restrict__ nlb,
    int* __restrict__ cnt, int* __restrict__ rlist, int* __restrict__ tokpos) {
  const int w = threadIdx.x >> 6, lane = threadIdx.x & 63;
  const int n = blockIdx.x * 4 + w;
  float val[4], s1v = 0.f, s2v = 0.f;
#pragma unroll
  for (int j = 0; j < 4; j++) {
    int d = lane + 64 * j;
    float v = o[(size_t)n * D + d] + x[(size_t)n * D + d];
    val[j] = v; s1v += v; s2v += v * v;
  }
#pragma unroll
  for (int m = 1; m < 64; m <<= 1) {
    s1v += __shfl_xor(s1v, m);
    s2v += __shfl_xor(s2v, m);
  }
  float mean = s1v * (1.f / D);
  float var = s2v * (1.f / D) - mean * mean;
  float rstd = rsqrtf(var + EPS);
  float ge[NE];
#pragma unroll
  for (int e = 0; e < NE; e++) ge[e] = 0.f;
#pragma unroll
  for (int j = 0; j < 4; j++) {
    int d = lane + 64 * j;
    float nv = (val[j] - mean) * rstd * s1[d] + b1[d];
    norm[(size_t)n * D + d] = nv;
    f16 h16, l16; splitf(nv, h16, l16);
    nhb[(size_t)n * D + d] = h16;
    nlb[(size_t)n * D + d] = l16;
    const float* gr = gW + (size_t)d * NE;
#pragma unroll
    for (int e = 0; e < NE; e++) ge[e] += nv * gr[e];
  }
#pragma unroll
  for (int m = 1; m < 64; m <<= 1)
#pragma unroll
    for (int e = 0; e < NE; e++) ge[e] += __shfl_xor(ge[e], m);
  if (lane == 0) {
#pragma unroll
    for (int e = 0; e < NE; e++) ge[e] += gb[e];
    int i1 = 0; float v1 = ge[0];
#pragma unroll
    for (int e = 1; e < NE; e++) if (ge[e] > v1) { v1 = ge[e]; i1 = e; }
    int i2 = -1; float v2 = -3.4e38f;
#pragma unroll
    for (int e = 0; e < NE; e++) if (e != i1 && ge[e] > v2) { v2 = ge[e]; i2 = e; }
    int p1 = atomicAdd(&cnt[i1], 1);
    int row1 = i1 * CAP + p1;
    rlist[row1] = n;
    tokpos[n * 2 + 0] = row1;
    int p2 = atomicAdd(&cnt[i2], 1);
    int row2 = i2 * CAP + p2;
    rlist[row2] = n;
    tokpos[n * 2 + 1] = row2;
  }
}

// ---------------- MoE up-projection: 128x64 tiles, K-step 64, dual GEMM ----------------
// grid (NE*4 tiles, 8 col-chunks), 256 thr
__global__ __launch_bounds__(256) void k_ff1_mfma(
    const f16* __restrict__ nhb, const f16* __restrict__ nlb,
    const int* __restrict__ cnt, const int* __restrict__ rlist,
    const f16* __restrict__ w1th, const f16* __restrict__ w1tl, const float* __restrict__ b1f,
    const f16* __restrict__ wgth, const f16* __restrict__ wgtl, const float* __restrict__ bgf,
    f16* __restrict__ hhb, f16* __restrict__ hlb) {
  const int e = blockIdx.x >> 2, tl = blockIdx.x & 3;
  const int cnt_e = cnt[e];
  if (tl * 128 >= cnt_e) return;
  const int nv0 = cnt_e - tl * 128;
  const int nv = nv0 < 128 ? nv0 : 128;
  const int base = e * CAP + tl * 128;
  const int col0 = blockIdx.y * 64;
  const f16* W1h = w1th + (size_t)e * D * FF + (size_t)col0 * D;
  const f16* W1l = w1tl + (size_t)e * D * FF + (size_t)col0 * D;
  const f16* Wgh = wgth + (size_t)e * D * FF + (size_t)col0 * D;
  const f16* Wgl = wgtl + (size_t)e * D * FF + (size_t)col0 * D;
  __shared__ f16 Ah[128][72], Al[128][72];
  __shared__ f16 B1h[64][72], B1l[64][72], B2h[64][72], B2l[64][72];
  __shared__ int rows[128];
  const int tid = threadIdx.x;
  if (tid < 128) rows[tid] = (tid < nv) ? rlist[base + tid] : 0;
  __syncthreads();
  const int asr = tid >> 1, asc = (tid & 1) * 32;
  const int bn2 = tid >> 2, bkc = (tid & 3) * 16;
  const int lane = tid & 63, w = tid >> 6;
  const int lm = lane & 15, lg = lane >> 4, lk = lg * 8;
  f32x4 acc1[2][4] = {}, acc2[2][4] = {};
  const int arow = rows[asr];
  for (int k0 = 0; k0 < D; k0 += 64) {
    {
      size_t ga = (size_t)arow * D + k0 + asc;
#pragma unroll
      for (int j = 0; j < 4; j++) {
        *(f16x8*)&Ah[asr][asc + j * 8] = *(const f16x8*)(nhb + ga + j * 8);
        *(f16x8*)&Al[asr][asc + j * 8] = *(const f16x8*)(nlb + ga + j * 8);
      }
      size_t gb = (size_t)bn2 * D + k0 + bkc;
#pragma unroll
      for (int j = 0; j < 2; j++) {
        *(f16x8*)&B1h[bn2][bkc + j * 8] = *(const f16x8*)(W1h + gb + j * 8);
        *(f16x8*)&B1l[bn2][bkc + j * 8] = *(const f16x8*)(W1l + gb + j * 8);
        *(f16x8*)&B2h[bn2][bkc + j * 8] = *(const f16x8*)(Wgh + gb + j * 8);
        *(f16x8*)&B2l[bn2][bkc + j * 8] = *(const f16x8*)(Wgl + gb + j * 8);
      }
    }
    __syncthreads();
#pragma unroll
    for (int ks = 0; ks < 2; ks++) {
      f16x8 a_h[2], a_l[2];
#pragma unroll
      for (int mt = 0; mt < 2; mt++) {
        a_h[mt] = *(const f16x8*)&Ah[w * 32 + mt * 16 + lm][ks * 32 + lk];
        a_l[mt] = *(const f16x8*)&Al[w * 32 + mt * 16 + lm][ks * 32 + lk];
      }
#pragma unroll
      for (int nt = 0; nt < 4; nt++) {
        f16x8 b_h = *(const f16x8*)&B1h[nt * 16 + lm][ks * 32 + lk];
        f16x8 b_l = *(const f16x8*)&B1l[nt * 16 + lm][ks * 32 + lk];
        f16x8 c_h = *(const f16x8*)&B2h[nt * 16 + lm][ks * 32 + lk];
        f16x8 c_l = *(const f16x8*)&B2l[nt * 16 + lm][ks * 32 + lk];
#pragma unroll
        for (int mt = 0; mt < 2; mt++) {
          f32x4 c1 = acc1[mt][nt];
          c1 = MFMA(a_h[mt], b_h, c1);
          c1 = MFMA(a_h[mt], b_l, c1);
          c1 = MFMA(a_l[mt], b_h, c1);
          acc1[mt][nt] = c1;
          f32x4 c2 = acc2[mt][nt];
          c2 = MFMA(a_h[mt], c_h, c2);
          c2 = MFMA(a_h[mt], c_l, c2);
          c2 = MFMA(a_l[mt], c_h, c2);
          acc2[mt][nt] = c2;
        }
      }
    }
    __syncthreads();
  }
#pragma unroll
  for (int mt = 0; mt < 2; mt++)
#pragma unroll
    for (int nt = 0; nt < 4; nt++) {
      int col = col0 + nt * 16 + lm;
      float bb1 = b1f[e * FF + col], bb2 = bgf[e * FF + col];
#pragma unroll
      for (int r = 0; r < 4; r++) {
        int rit = w * 32 + mt * 16 + lg * 4 + r;
        if (rit < nv) {
          float z1 = acc1[mt][nt][r] + bb1;
          float zg = acc2[mt][nt][r] + bb2;
          float sl = z1 / (1.f + expf(-z1));
          float hv = sl * zg;
          f16 h16, l16; splitf(hv, h16, l16);
          hhb[(size_t)(base + rit) * FF + col] = h16;
          hlb[(size_t)(base + rit) * FF + col] = l16;
        }
      }
    }
}

// ---------------- MoE down-projection: 128x64 tiles, K-step 64 ----------------
// grid (NE*4 tiles, 4 col-chunks), 256 thr
__global__ __launch_bounds__(256) void k_ff2_mfma(
    const f16* __restrict__ hhb, const f16* __restrict__ hlb,
    const int* __restrict__ cnt,
    const f16* __restrict__ w2th, const f16* __restrict__ w2tl, const float* __restrict__ b2f,
    float* __restrict__ ybuf) {
  const int e = blockIdx.x >> 2, tl = blockIdx.x & 3;
  const int cnt_e = cnt[e];
  if (tl * 128 >= cnt_e) return;
  const int nv0 = cnt_e - tl * 128;
  const int nv = nv0 < 128 ? nv0 : 128;
  const int base = e * CAP + tl * 128;
  const int col0 = blockIdx.y * 64;
  const f16* W2h = w2th + (size_t)e * FF * D + (size_t)col0 * FF;
  const f16* W2l = w2tl + (size_t)e * FF * D + (size_t)col0 * FF;
  __shared__ f16 Ah[128][72], Al[128][72], Bh[64][72], Bl[64][72];
  const int tid = threadIdx.x;
  const int asr = tid >> 1, asc = (tid & 1) * 32;
  const int bn2 = tid >> 2, bkc = (tid & 3) * 16;
  const int lane = tid & 63, w = tid >> 6;
  const int lm = lane & 15, lg = lane >> 4, lk = lg * 8;
  f32x4 acc[2][4] = {};
  for (int k0 = 0; k0 < FF; k0 += 64) {
    {
      size_t ga = (size_t)(base + asr) * FF + k0 + asc;
#pragma unroll
      for (int j = 0; j < 4; j++) {
        *(f16x8*)&Ah[asr][asc + j * 8] = *(const f16x8*)(hhb + ga + j * 8);
        *(f16x8*)&Al[asr][asc + j * 8] = *(const f16x8*)(hlb + ga + j * 8);
      }
      size_t gb = (size_t)bn2 * FF + k0 + bkc;
#pragma unroll
      for (int j = 0; j < 2; j++) {
        *(f16x8*)&Bh[bn2][bkc + j * 8] = *(const f16x8*)(W2h + gb + j * 8);
        *(f16x8*)&Bl[bn2][bkc + j * 8] = *(const f16x8*)(W2l + gb + j * 8);
      }
    }
    __syncthreads();
#pragma unroll
    for (int ks = 0; ks < 2; ks++) {
      f16x8 a_h[2], a_l[2];
#pragma unroll
      for (int mt = 0; mt < 2; mt++) {
        a_h[mt] = *(const f16x8*)&Ah[w * 32 + mt * 16 + lm][ks * 32 + lk];
        a_l[mt] = *(const f16x8*)&Al[w * 32 + mt * 16 + lm][ks * 32 + lk];
      }
#pragma unroll
      for (int nt = 0; nt < 4; nt++) {
        f16x8 b_h = *(const f16x8*)&Bh[nt * 16 + lm][ks * 32 + lk];
        f16x8 b_l = *(const f16x8*)&Bl[nt * 16 + lm][ks * 32 + lk];
#pragma unroll
        for (int mt = 0; mt < 2; mt++) {
          f32x4 c = acc[mt][nt];
          c = MFMA(a_h[mt], b_h, c);
          c = MFMA(a_h[mt], b_l, c);
          c = MFMA(a_l[mt], b_h, c);
          acc[mt][nt] = c;
        }
      }
    }
    __syncthreads();
  }
#pragma unroll
  for (int mt = 0; mt < 2; mt++)
#pragma unroll
    for (int nt = 0; nt < 4; nt++) {
      int col = col0 + nt * 16 + lm;
      float bb = b2f[e * D + col];
#pragma unroll
      for (int r = 0; r < 4; r++) {
        int rit = w * 32 + mt * 16 + lg * 4 + r;
        if (rit < nv) ybuf[(size_t)(base + rit) * D + col] = acc[mt][nt][r] + bb;
      }
    }
}

// ---------------- wave-per-token: moe-sum + residual + LN2 + split ----------------
// grid 512, 256 thr
__global__ __launch_bounds__(256) void k_ln2(
    const float* __restrict__ ybuf, const int* __restrict__ tokpos,
    const float* __restrict__ norm, const float* __restrict__ s2, const float* __restrict__ b2,
    float* __restrict__ dst, f16* __restrict__ xh, f16* __restrict__ xl) {
  const int w = threadIdx.x >> 6, lane = threadIdx.x & 63;
  const int n = blockIdx.x * 4 + w;
  const int p0 = tokpos[n * 2 + 0], p1 = tokpos[n * 2 + 1];
  float val[4], s1v = 0.f, s2v = 0.f;
#pragma unroll
  for (int j = 0; j < 4; j++) {
    int d = lane + 64 * j;
    float v = ybuf[(size_t)p0 * D + d] + ybuf[(size_t)p1 * D + d] + norm[(size_t)n * D + d];
    val[j] = v; s1v += v; s2v += v * v;
  }
#pragma unroll
  for (int m = 1; m < 64; m <<= 1) {
    s1v += __shfl_xor(s1v, m);
    s2v += __shfl_xor(s2v, m);
  }
  float mean = s1v * (1.f / D);
  float var = s2v * (1.f / D) - mean * mean;
  float rstd = rsqrtf(var + EPS);
#pragma unroll
  for (int j = 0; j < 4; j++) {
    int d = lane + 64 * j;
    float ov = (val[j] - mean) * rstd * s2[d] + b2[d];
    dst[(size_t)n * D + d] = ov;
    f16 h16, l16; splitf(ov, h16, l16);
    xh[(size_t)n * D + d] = h16;
    xl[(size_t)n * D + d] = l16;
  }
}

extern "C" void kernel_launch(void* const* d_in, const int* in_sizes, int n_in,
                              void* d_out, int out_size, void* d_ws, size_t ws_size,
                              hipStream_t stream) {
  (void)in_sizes; (void)n_in; (void)out_size; (void)ws_size;
  const int*   tok = (const int*)d_in[0];
  const float* emb = (const float*)d_in[1];
  const float* Wq  = (const float*)d_in[2];
  const float* bq  = (const float*)d_in[3];
  const float* Wk  = (const float*)d_in[4];
  const float* bk  = (const float*)d_in[5];
  const float* Wv  = (const float*)d_in[6];
  const float* bv  = (const float*)d_in[7];
  const float* l1s = (const float*)d_in[8];
  const float* l1b = (const float*)d_in[9];
  const float* l2s = (const float*)d_in[10];
  const float* l2b = (const float*)d_in[11];
  const float* gW  = (const float*)d_in[12];
  const float* gb  = (const float*)d_in[13];
  const float* f1W = (const float*)d_in[14];
  const float* f1b = (const float*)d_in[15];
  const float* fgW = (const float*)d_in[16];
  const float* fgb = (const float*)d_in[17];
  const float* f2W = (const float*)d_in[18];
  const float* f2b = (const float*)d_in[19];
  float* out = (float*)d_out;

  char* p = (char*)d_ws;
  auto alloc = [&](size_t bytes) { char* r = p; p += (bytes + 255) & ~(size_t)255; return r; };
  // activations
  float* xb = (float*)alloc((size_t)NT * D * 4);
  f16* xh = (f16*)alloc((size_t)NT * D * 2);
  f16* xl = (f16*)alloc((size_t)NT * D * 2);
  f16* qhb = (f16*)alloc((size_t)NT * D * 2);
  f16* qlb = (f16*)alloc((size_t)NT * D * 2);
  f16* khb = (f16*)alloc((size_t)NT * D * 2);
  f16* klb = (f16*)alloc((size_t)NT * D * 2);
  f16* vhb = (f16*)alloc((size_t)NT * D * 2);
  f16* vlb = (f16*)alloc((size_t)NT * D * 2);
  float* ob = (float*)alloc((size_t)NT * D * 4);
  float* nb = (float*)alloc((size_t)NT * D * 4);
  f16* nhb = (f16*)alloc((size_t)NT * D * 2);
  f16* nlb = (f16*)alloc((size_t)NT * D * 2);
  f16* hhb = (f16*)alloc((size_t)ROWSP * FF * 2);
  f16* hlb = (f16*)alloc((size_t)ROWSP * FF * 2);
  float* yb = (float*)alloc((size_t)ROWSP * D * 4);
  int* cntbuf = (int*)alloc((size_t)LNUM * NE * 4);
  int* rlist  = (int*)alloc((size_t)ROWSP * 4);
  int* tokpos = (int*)alloc((size_t)NT * 2 * 4);
  // pre-split/transposed weights
  size_t qkvsz = (size_t)LNUM * D * D;        // per hi/lo, elements
  size_t ffsz  = (size_t)LNUM * NE * D * FF;  // per hi/lo, elements
  f16* wqh = (f16*)alloc(qkvsz * 2); f16* wql = (f16*)alloc(qkvsz * 2);
  f16* wkh = (f16*)alloc(qkvsz * 2); f16* wkl = (f16*)alloc(qkvsz * 2);
  f16* wvh = (f16*)alloc(qkvsz * 2); f16* wvl = (f16*)alloc(qkvsz * 2);
  f16* w1th = (f16*)alloc(ffsz * 2); f16* w1tl = (f16*)alloc(ffsz * 2);
  f16* wgth = (f16*)alloc(ffsz * 2); f16* wgtl = (f16*)alloc(ffsz * 2);
  f16* w2th = (f16*)alloc(ffsz * 2); f16* w2tl = (f16*)alloc(ffsz * 2);

  // ---- weight prep (per launch; deterministic) ----
  k_wprep<<<dim3(D / 32, D / 32, LNUM), 256, 0, stream>>>(Wq, wqh, wql, D, D);
  k_wprep<<<dim3(D / 32, D / 32, LNUM), 256, 0, stream>>>(Wk, wkh, wkl, D, D);
  k_wprep<<<dim3(D / 32, D / 32, LNUM), 256, 0, stream>>>(Wv, wvh, wvl, D, D);
  k_wprep<<<dim3(FF / 32, D / 32, LNUM * NE), 256, 0, stream>>>(f1W, w1th, w1tl, D, FF);
  k_wprep<<<dim3(FF / 32, D / 32, LNUM * NE), 256, 0, stream>>>(fgW, wgth, wgtl, D, FF);
  k_wprep<<<dim3(D / 32, FF / 32, LNUM * NE), 256, 0, stream>>>(f2W, w2th, w2tl, FF, D);

  k_embed<<<NT, 256, 0, stream>>>(tok, emb, xb, xh, xl, cntbuf);

  for (int l = 0; l < LNUM; l++) {
    int* cnt = cntbuf + l * NE;
    k_qkv_mfma<<<dim3(16, 4, 3), 256, 0, stream>>>(
        xh, xl,
        wqh + (size_t)l * D * D, wql + (size_t)l * D * D, bq + (size_t)l * D,
        wkh + (size_t)l * D * D, wkl + (size_t)l * D * D, bk + (size_t)l * D,
        wvh + (size_t)l * D * D, wvl + (size_t)l * D * D, bv + (size_t)l * D,
        qhb, qlb, khb, klb, vhb, vlb);
    k_attn_mfma<<<dim3(8, 32), 256, 0, stream>>>(qhb, qlb, khb, klb, vhb, vlb, ob);
    k_ln1gate<<<NT / 4, 256, 0, stream>>>(ob, xb, l1s + (size_t)l * D, l1b + (size_t)l * D,
                                          gW + (size_t)l * D * NE, gb + (size_t)l * NE,
                                          nb, nhb, nlb, cnt, rlist, tokpos);
    k_ff1_mfma<<<dim3(NE * 4, 8), 256, 0, stream>>>(
        nhb, nlb, cnt, rlist,
        w1th + (size_t)l * NE * D * FF, w1tl + (size_t)l * NE * D * FF, f1b + (size_t)l * NE * FF,
        wgth + (size_t)l * NE * D * FF, wgtl + (size_t)l * NE * D * FF, fgb + (size_t)l * NE * FF,
        hhb, hlb);
    k_ff2_mfma<<<dim3(NE * 4, 4), 256, 0, stream>>>(
        hhb, hlb, cnt,
        w2th + (size_t)l * NE * FF * D, w2tl + (size_t)l * NE * FF * D, f2b + (size_t)l * NE * D,
        yb);
    k_ln2<<<NT / 4, 256, 0, stream>>>(yb, tokpos, nb, l2s + (size_t)l * D, l2b + (size_t)l * D,
                                      (l == LNUM - 1) ? out : xb, xh, xl);
  }
}